// Round 1
// 1319.261 us; speedup vs baseline: 1.5877x; 1.5877x over previous
//
#include <hip/hip_runtime.h>
#include <hip/hip_bf16.h>

#define BB 32
#define SS 2048
#define DD 64
#define NTH 256
#define QT 16      // q rows per block
#define KTL 128    // k per stage tile
#define SCALE 0.125f   // 1/sqrt(64)

typedef __attribute__((ext_vector_type(4))) float f32x4;
typedef __attribute__((ext_vector_type(8))) short bf16x8;

union B8 { bf16x8 v; unsigned int u[4]; };

// pack 2 f32 -> packed bf16 pair (v_cvt_pk_bf16_f32 on gfx950)
__device__ __forceinline__ unsigned int pk2bf(float a, float b) {
    __hip_bfloat162 h = __float22bfloat162_rn(make_float2(a, b));
    unsigned int u;
    __builtin_memcpy(&u, &h, 4);
    return u;
}
__device__ __forceinline__ float bf_lo(unsigned int w) {
    return __builtin_bit_cast(float, w << 16);
}
__device__ __forceinline__ float bf_hi(unsigned int w) {
    return __builtin_bit_cast(float, w & 0xffff0000u);
}

// Block: (batch b, 16 q-rows) x all 2048 keys. 4 waves; wave w owns keys
// [w*32, w*32+32) of each 128-key tile for BOTH QK^T and P@V.
// Two sweeps over K: sweep1 = scores+exp+rowsum (mask -> 128-bit reg cache),
// sweep2 = recompute scores, write normalized attn, P@V via MFMA.
// All MFMA A/B fragments built with slot->k map k=(lane>>4)*8+j on BOTH
// operands -> contraction is permutation-invariant (no dependence on the
// HW's internal k ordering). C/D layout: col=lane&15, row=(lane>>4)*4+reg.
__global__ __launch_bounds__(NTH, 3) void sdpa_mfma(
    const float* __restrict__ Q, const float* __restrict__ K,
    const float* __restrict__ V, const int* __restrict__ M,
    float* __restrict__ ctx, float* __restrict__ attn)
{
    // LDS carve-up: K 16 KB | VT2 32 KB | bounce 4 KB  (53248 B -> 3 blocks/CU)
    __shared__ __align__(16) unsigned char smem[53248];
    unsigned short* k_lds = (unsigned short*)smem;            // [128][64] bf16, row-swizzled
    unsigned int*   vt2   = (unsigned int*)(smem + 16384);    // [64][128] u32 (lo=Vh, hi=Vl), swizzled
    unsigned short* bnc   = (unsigned short*)(smem + 49152);  // 1 KB per wave: P shuffle bounce
    float*          scr   = (float*)smem;                     // epilogue ctx scratch (17 KB, overlays)
    __shared__ float wsum[4][QT];
    __shared__ float inv_l[QT];

    const int t    = threadIdx.x;
    const int wave = t >> 6, l = t & 63, g = l >> 4, li = l & 15;
    const int b    = blockIdx.x >> 7;
    const int q0   = (blockIdx.x & 127) * QT;

    const float* Kb  = K + (size_t)b * SS * DD;
    const float* Vb  = V + (size_t)b * SS * DD;
    const int*   Mb  = M + ((size_t)b * SS + q0) * SS;
    float*      attb = attn + ((size_t)b * SS + q0) * SS;

    // ---- Q fragments, split hi+lo bf16 (quasi-exact). A-frag: m=li, k=g*8+j (+32h) ----
    B8 qh[2], ql[2];
    {
        const float* qp = Q + ((size_t)(b * SS + q0 + li)) * DD + g * 8;
        #pragma unroll
        for (int h = 0; h < 2; ++h) {
            float f[8];
            *(float4*)&f[0] = *(const float4*)(qp + h * 32);
            *(float4*)&f[4] = *(const float4*)(qp + h * 32 + 4);
            #pragma unroll
            for (int i = 0; i < 4; ++i) {
                unsigned int hw = pk2bf(f[2*i], f[2*i+1]);
                qh[h].u[i] = hw;
                ql[h].u[i] = pk2bf(f[2*i] - bf_lo(hw), f[2*i+1] - bf_hi(hw));
            }
        }
    }

    // K tile -> LDS bf16, row kc swizzled: byte = (kc*128 + d*2) ^ ((kc&7)<<4)
    auto stageK = [&](int tl) {
        const float4* Ks = (const float4*)(Kb + (size_t)tl * KTL * DD);
        #pragma unroll
        for (int i = 0; i < 8; ++i) {
            const int f4 = i * NTH + t;                 // coalesced
            float4 kv = Ks[f4];
            const int kc = f4 >> 4, d4 = f4 & 15;
            const int by = (kc * 128 + d4 * 8) ^ ((kc & 7) << 4);
            uint2 wv;
            wv.x = pk2bf(kv.x, kv.y);
            wv.y = pk2bf(kv.z, kv.w);
            *(uint2*)((unsigned char*)k_lds + by) = wv;
        }
    };

    // QK^T for this wave's 32 keys of the staged tile. s0: keys wave*32+li, s1: +16.
    auto qk = [&](f32x4& s0, f32x4& s1) {
        const int kc0 = wave * 32 + li, kc1 = kc0 + 16;
        #pragma unroll
        for (int h = 0; h < 2; ++h) {
            const int off = h * 64 + g * 16;            // bytes: d = 32h + 8g
            B8 kb0, kb1;
            kb0.v = *(const bf16x8*)((unsigned char*)k_lds + ((kc0 * 128 + off) ^ ((kc0 & 7) << 4)));
            kb1.v = *(const bf16x8*)((unsigned char*)k_lds + ((kc1 * 128 + off) ^ ((kc1 & 7) << 4)));
            s0 = __builtin_amdgcn_mfma_f32_16x16x32_bf16(qh[h].v, kb0.v, s0, 0, 0, 0);
            s0 = __builtin_amdgcn_mfma_f32_16x16x32_bf16(ql[h].v, kb0.v, s0, 0, 0, 0);
            s1 = __builtin_amdgcn_mfma_f32_16x16x32_bf16(qh[h].v, kb1.v, s1, 0, 0, 0);
            s1 = __builtin_amdgcn_mfma_f32_16x16x32_bf16(ql[h].v, kb1.v, s1, 0, 0, 0);
        }
    };

    // ---- sweep 1: scores -> exp -> row sums; mask cached as bits in regs ----
    float lsum[4] = {0.f, 0.f, 0.f, 0.f};
    unsigned int mb0 = 0, mb1 = 0, mb2 = 0, mb3 = 0;

    #pragma unroll 1
    for (int tl = 0; tl < 16; ++tl) {
        __syncthreads();
        stageK(tl);
        __syncthreads();
        const int kg0 = tl * KTL + wave * 32 + li;
        int m0a[4], m1a[4];
        #pragma unroll
        for (int r = 0; r < 4; ++r) {                   // issue mask loads early
            const size_t mo = (size_t)(g * 4 + r) * SS + kg0;
            m0a[r] = __builtin_nontemporal_load(&Mb[mo]);
            m1a[r] = __builtin_nontemporal_load(&Mb[mo + 16]);
        }
        f32x4 s0 = {0.f,0.f,0.f,0.f}, s1 = {0.f,0.f,0.f,0.f};
        qk(s0, s1);
        unsigned int fl = 0;
        #pragma unroll
        for (int r = 0; r < 4; ++r) {
            float e0 = __expf(s0[r] * SCALE);
            float e1 = __expf(s1[r] * SCALE);
            if (m0a[r]) { fl |= 1u << r;       e0 = 0.f; }
            if (m1a[r]) { fl |= 1u << (4 + r); e1 = 0.f; }
            lsum[r] += e0 + e1;
        }
        mb0 = (mb0 >> 8) | (mb1 << 24);
        mb1 = (mb1 >> 8) | (mb2 << 24);
        mb2 = (mb2 >> 8) | (mb3 << 24);
        mb3 = (mb3 >> 8) | (fl << 24);
    }

    // ---- row sums: reduce over the 16 lanes sharing a row-quartet, then cross-wave ----
    #pragma unroll
    for (int off = 8; off >= 1; off >>= 1)
        #pragma unroll
        for (int r = 0; r < 4; ++r)
            lsum[r] += __shfl_xor(lsum[r], off, 64);
    if (li == 0) {
        #pragma unroll
        for (int r = 0; r < 4; ++r) wsum[wave][g * 4 + r] = lsum[r];
    }
    __syncthreads();
    if (t < QT) inv_l[t] = 1.0f / (wsum[0][t] + wsum[1][t] + wsum[2][t] + wsum[3][t]);
    __syncthreads();
    float invl[4];
    #pragma unroll
    for (int r = 0; r < 4; ++r) invl[r] = inv_l[g * 4 + r];

    // ---- sweep 2: recompute scores, write normalized attn, P@V via MFMA ----
    f32x4 cacc[4] = {{0.f,0.f,0.f,0.f},{0.f,0.f,0.f,0.f},{0.f,0.f,0.f,0.f},{0.f,0.f,0.f,0.f}};
    unsigned short* bw = bnc + wave * 512;

    #pragma unroll 1
    for (int tl = 0; tl < 16; ++tl) {
        __syncthreads();
        stageK(tl);
        {   // V tile -> VT2[d][k] u32 (lo=bf16(V) hi=bf16(resid)), swizzle ^(((d>>2)&7)<<2) on word idx
            const float4* Vs = (const float4*)(Vb + (size_t)tl * KTL * DD);
            #pragma unroll
            for (int i = 0; i < 4; ++i) {
                const int task = i * NTH + t;
                const int d4 = task & 15, k0 = (task >> 4) * 2;
                float4 va = Vs[k0 * 16 + d4];
                float4 vb = Vs[k0 * 16 + 16 + d4];
                const float* pa = (const float*)&va;
                const float* pb = (const float*)&vb;
                #pragma unroll
                for (int ww = 0; ww < 4; ++ww) {
                    const int d = d4 * 4 + ww;
                    unsigned int hp = pk2bf(pa[ww], pb[ww]);
                    unsigned int lp = pk2bf(pa[ww] - bf_lo(hp), pb[ww] - bf_hi(hp));
                    uint2 wv;
                    wv.x = (hp & 0xffffu) | (lp << 16);
                    wv.y = (hp >> 16) | (lp & 0xffff0000u);
                    const int widx = (d * 128 + k0) ^ (((d >> 2) & 7) << 2);
                    *(uint2*)&vt2[widx] = wv;
                }
            }
        }
        __syncthreads();
        f32x4 s0 = {0.f,0.f,0.f,0.f}, s1 = {0.f,0.f,0.f,0.f};
        qk(s0, s1);
        const unsigned int fl = mb0 & 0xffu;
        mb0 = (mb0 >> 8) | (mb1 << 24);
        mb1 = (mb1 >> 8) | (mb2 << 24);
        mb2 = (mb2 >> 8) | (mb3 << 24);
        mb3 >>= 8;
        const int kg0 = tl * KTL + wave * 32 + li;
        #pragma unroll
        for (int r = 0; r < 4; ++r) {
            float e0 = ((fl >> r)       & 1u) ? 0.f : __expf(s0[r] * SCALE);
            float e1 = ((fl >> (4 + r)) & 1u) ? 0.f : __expf(s1[r] * SCALE);
            const size_t ao = (size_t)(g * 4 + r) * SS + kg0;
            attb[ao]      = e0 * invl[r];               // plain stores: let L2 assemble lines
            attb[ao + 16] = e1 * invl[r];
            // bounce: value (q=g*4+r, kk) -> slot ((kk>>3)<<7) + q*8 + (kk&7); kk = li / li+16
            bw[((li >> 3) << 7)        + (g * 4 + r) * 8 + (li & 7)] = (unsigned short)pk2bf(e0, 0.f);
            bw[(((li + 16) >> 3) << 7) + (g * 4 + r) * 8 + (li & 7)] = (unsigned short)pk2bf(e1, 0.f);
        }
        // P A-frag: lane reads its 16 B (q=li, k=g*8+j) — same-wave LDS, compiler orders
        B8 pf;
        pf.v = *(const bf16x8*)(bw + l * 8);
        #pragma unroll
        for (int c = 0; c < 4; ++c) {
            const int d    = c * 16 + li;
            const int base = d * 128 + wave * 32 + g * 8;
            const int sw   = ((d >> 2) & 7) << 2;
            uint4 wa = *(const uint4*)&vt2[(base) ^ sw];
            uint4 wb = *(const uint4*)&vt2[(base + 4) ^ sw];
            B8 vhf, vlf;
            vhf.u[0] = __builtin_amdgcn_perm(wa.y, wa.x, 0x05040100u);
            vlf.u[0] = __builtin_amdgcn_perm(wa.y, wa.x, 0x07060302u);
            vhf.u[1] = __builtin_amdgcn_perm(wa.w, wa.z, 0x05040100u);
            vlf.u[1] = __builtin_amdgcn_perm(wa.w, wa.z, 0x07060302u);
            vhf.u[2] = __builtin_amdgcn_perm(wb.y, wb.x, 0x05040100u);
            vlf.u[2] = __builtin_amdgcn_perm(wb.y, wb.x, 0x07060302u);
            vhf.u[3] = __builtin_amdgcn_perm(wb.w, wb.z, 0x05040100u);
            vlf.u[3] = __builtin_amdgcn_perm(wb.w, wb.z, 0x07060302u);
            cacc[c] = __builtin_amdgcn_mfma_f32_16x16x32_bf16(pf.v, vhf.v, cacc[c], 0, 0, 0);
            cacc[c] = __builtin_amdgcn_mfma_f32_16x16x32_bf16(pf.v, vlf.v, cacc[c], 0, 0, 0);
        }
    }

    // ---- ctx: cross-wave reduce via scratch (k_lds/vt2 dead), scale by 1/L ----
    __syncthreads();
    {
        const int row = wave * 64 + l;                  // 256 rows x 17 floats (pad: stride 17)
        #pragma unroll
        for (int c = 0; c < 4; ++c)
            #pragma unroll
            for (int r = 0; r < 4; ++r)
                scr[row * 17 + c * 4 + r] = cacc[c][r];
    }
    __syncthreads();
    {
        const int q = t >> 4, d0 = (t & 15) * 4;
        float4 o;
        float* op = &o.x;
        #pragma unroll
        for (int dd = 0; dd < 4; ++dd) {
            const int d    = d0 + dd;
            const int lane = (q >> 2) * 16 + (d & 15);
            const int idx  = lane * 17 + (d >> 4) * 4 + (q & 3);
            float s = 0.f;
            #pragma unroll
            for (int w = 0; w < 4; ++w) s += scr[w * 64 * 17 + idx];
            op[dd] = s * inv_l[q];
        }
        *(float4*)(ctx + ((size_t)(b * SS + q0 + q)) * DD + d0) = o;
    }
}

extern "C" void kernel_launch(void* const* d_in, const int* in_sizes, int n_in,
                              void* d_out, int out_size, void* d_ws, size_t ws_size,
                              hipStream_t stream) {
    const float* Q = (const float*)d_in[0];
    const float* K = (const float*)d_in[1];
    const float* V = (const float*)d_in[2];
    const int*   M = (const int*)d_in[3];
    float* ctx  = (float*)d_out;                               // [32,2048,64]
    float* attn = (float*)d_out + (size_t)BB * SS * DD;        // [32,2048,2048]
    sdpa_mfma<<<dim3(BB * (SS / QT)), dim3(NTH), 0, stream>>>(Q, K, V, M, ctx, attn);
}

// Round 2
// 1286.787 us; speedup vs baseline: 1.6278x; 1.0252x over previous
//
#include <hip/hip_runtime.h>
#include <hip/hip_bf16.h>

#define BB 32
#define SS 2048
#define DD 64
#define NTH 256
#define QT 16      // q rows per block
#define KTL 128    // k per tile
#define SCALE 0.125f   // 1/sqrt(64)

typedef __attribute__((ext_vector_type(4))) float f32x4;
typedef __attribute__((ext_vector_type(8))) short bf16x8;

union B8 { bf16x8 v; unsigned int u[4]; };

// pack 2 f32 -> packed bf16 pair (v_cvt_pk_bf16_f32 on gfx950)
__device__ __forceinline__ unsigned int pk2bf(float a, float b) {
    __hip_bfloat162 h = __float22bfloat162_rn(make_float2(a, b));
    unsigned int u;
    __builtin_memcpy(&u, &h, 4);
    return u;
}
__device__ __forceinline__ float bf_lo(unsigned int w) {
    return __builtin_bit_cast(float, w << 16);
}
__device__ __forceinline__ float bf_hi(unsigned int w) {
    return __builtin_bit_cast(float, w & 0xffff0000u);
}

// ---------------- pre-kernel A: K f32 -> bf16, layout preserved [b][k][d] ----------------
__global__ __launch_bounds__(NTH) void prepK(const float* __restrict__ K,
                                             unsigned short* __restrict__ Kbf) {
    const size_t i = (size_t)blockIdx.x * NTH + threadIdx.x;   // 524288 threads, 8 elems each
    const float4* s = (const float4*)K;
    const float4 a = s[2 * i], c = s[2 * i + 1];
    uint4 w;
    w.x = pk2bf(a.x, a.y); w.y = pk2bf(a.z, a.w);
    w.z = pk2bf(c.x, c.y); w.w = pk2bf(c.z, c.w);
    ((uint4*)Kbf)[i] = w;
}

// ------- pre-kernel B: V [b][k][d] f32 -> VTh/VTl [b][d][k] bf16 (hi + residual-lo) -------
#define VPADF 68
__global__ __launch_bounds__(NTH) void prepV(const float* __restrict__ V,
                                             unsigned short* __restrict__ VTh,
                                             unsigned short* __restrict__ VTl) {
    __shared__ __align__(16) float lt[KTL * VPADF];            // 34816 B
    const int t  = threadIdx.x;
    const int b  = blockIdx.x >> 4;
    const int ck = blockIdx.x & 15;                            // 128-key chunk
    const float4* Vs = (const float4*)(V + ((size_t)b * SS + ck * KTL) * DD);
    #pragma unroll
    for (int i = 0; i < 8; ++i) {
        const int f4 = i * NTH + t;                            // coalesced
        float4 v = Vs[f4];
        const int kc = f4 >> 4, d4 = f4 & 15;
        *(float4*)&lt[kc * VPADF + d4 * 4] = v;
    }
    __syncthreads();
    const int d = t >> 2, kseg = t & 3;                        // d 0..63, 32 keys per kseg
    unsigned short* oh = VTh + ((size_t)b * DD + d) * SS + ck * KTL + kseg * 32;
    unsigned short* ol = VTl + ((size_t)b * DD + d) * SS + ck * KTL + kseg * 32;
    #pragma unroll
    for (int cch = 0; cch < 4; ++cch) {
        uint4 wh, wl;
        unsigned int* ph = (unsigned int*)&wh;
        unsigned int* pl = (unsigned int*)&wl;
        #pragma unroll
        for (int p = 0; p < 4; ++p) {
            const int k0 = kseg * 32 + cch * 8 + p * 2;
            const float a = lt[k0 * VPADF + d], c = lt[(k0 + 1) * VPADF + d];
            const unsigned int hw = pk2bf(a, c);
            ph[p] = hw;
            pl[p] = pk2bf(a - bf_lo(hw), c - bf_hi(hw));
        }
        *(uint4*)(oh + cch * 8) = wh;
        *(uint4*)(ol + cch * 8) = wl;
    }
}

// ---------------- main kernel ----------------
// Block: (batch b, 16 q rows) x 2048 keys; 4 waves, wave owns keys w*32..+32 of each tile.
// K fragments and V^T fragments are read DIRECTLY from global (L2-resident bf16 prepared
// by pre-kernels) -> no K/V LDS staging, no __syncthreads in either K-sweep. Only LDS:
// 1 KB/wave P-bounce (wave-local) + epilogue scratch (overlaid). 4 barriers per block.
// Sweep 1: QK^T -> exp -> row sums; mask cached as 128 reg bits. Sweep 2: recompute
// scores (cheap: 4 loads + 8 MFMA), write normalized attn, P@V via MFMA (V hi+lo).
// Frag maps (16x16x32): A: lane l holds A[m=l&15][k=(l>>4)*8+j]; B: B[k=(l>>4)*8+j][n=l&15];
// C: C[m=(l>>4)*4+r][n=l&15]. Same k-slot map on both operands -> permutation-invariant.
__global__ __launch_bounds__(NTH, 4) void sdpa_mfma2(
    const float* __restrict__ Q, const int* __restrict__ M,
    const unsigned short* __restrict__ Kbf,
    const unsigned short* __restrict__ VTh, const unsigned short* __restrict__ VTl,
    float* __restrict__ ctx, float* __restrict__ attn)
{
    __shared__ __align__(16) unsigned char smem[17408];        // bnc 4 KB / scr 17 KB (overlaid)
    __shared__ float wsum[4][QT];
    __shared__ float inv_l[QT];
    unsigned short* bnc = (unsigned short*)smem;
    float*          scr = (float*)smem;

    const int t    = threadIdx.x;
    const int wave = t >> 6, l = t & 63, g = l >> 4, li = l & 15;
    const int b    = blockIdx.x >> 7;
    const int q0   = (blockIdx.x & 127) * QT;

    const unsigned short* Kb  = Kbf + (size_t)b * SS * DD;
    const unsigned short* Vhb = VTh + (size_t)b * DD * SS;
    const unsigned short* Vlb = VTl + (size_t)b * DD * SS;
    const int*   Mb   = M + ((size_t)b * SS + q0) * SS;
    float*       attb = attn + ((size_t)b * SS + q0) * SS;

    // ---- Q fragments, split hi+lo bf16 (quasi-exact). m=li, k=g*8+j (+32h) ----
    B8 qh[2], ql[2];
    {
        const float* qp = Q + ((size_t)(b * SS + q0 + li)) * DD + g * 8;
        #pragma unroll
        for (int h = 0; h < 2; ++h) {
            float f[8];
            *(float4*)&f[0] = *(const float4*)(qp + h * 32);
            *(float4*)&f[4] = *(const float4*)(qp + h * 32 + 4);
            #pragma unroll
            for (int i = 0; i < 4; ++i) {
                unsigned int hw = pk2bf(f[2*i], f[2*i+1]);
                qh[h].u[i] = hw;
                ql[h].u[i] = pk2bf(f[2*i] - bf_lo(hw), f[2*i+1] - bf_hi(hw));
            }
        }
    }

    // per-lane K fragment base: row kc0 = wave*32+li, col byte for d = g*8
    const unsigned short* kf0 = Kb + (size_t)(wave * 32 + li) * DD + g * 8;

    auto qk = [&](int tl, f32x4& s0, f32x4& s1) {
        const unsigned short* p0 = kf0 + (size_t)tl * KTL * DD;
        #pragma unroll
        for (int h = 0; h < 2; ++h) {
            B8 k0, k1;
            k0.v = *(const bf16x8*)(p0 + 32 * h);              // row kc0, L2-hit
            k1.v = *(const bf16x8*)(p0 + 16 * DD + 32 * h);    // row kc0+16
            s0 = __builtin_amdgcn_mfma_f32_16x16x32_bf16(qh[h].v, k0.v, s0, 0, 0, 0);
            s0 = __builtin_amdgcn_mfma_f32_16x16x32_bf16(ql[h].v, k0.v, s0, 0, 0, 0);
            s1 = __builtin_amdgcn_mfma_f32_16x16x32_bf16(qh[h].v, k1.v, s1, 0, 0, 0);
            s1 = __builtin_amdgcn_mfma_f32_16x16x32_bf16(ql[h].v, k1.v, s1, 0, 0, 0);
        }
    };

    // ---- sweep 1: scores -> exp -> row sums; mask -> 128 reg bits. NO barriers. ----
    float lsum[4] = {0.f, 0.f, 0.f, 0.f};
    unsigned int mb0 = 0, mb1 = 0, mb2 = 0, mb3 = 0;

    #pragma unroll 1
    for (int tl = 0; tl < 16; ++tl) {
        const int kg0 = tl * KTL + wave * 32 + li;
        int m0a[4], m1a[4];
        #pragma unroll
        for (int r = 0; r < 4; ++r) {
            const size_t mo = (size_t)(g * 4 + r) * SS + kg0;
            m0a[r] = __builtin_nontemporal_load(&Mb[mo]);
            m1a[r] = __builtin_nontemporal_load(&Mb[mo + 16]);
        }
        f32x4 s0 = {0.f,0.f,0.f,0.f}, s1 = {0.f,0.f,0.f,0.f};
        qk(tl, s0, s1);
        unsigned int fl = 0;
        #pragma unroll
        for (int r = 0; r < 4; ++r) {
            float e0 = __expf(s0[r] * SCALE);
            float e1 = __expf(s1[r] * SCALE);
            if (m0a[r]) { fl |= 1u << r;       e0 = 0.f; }
            if (m1a[r]) { fl |= 1u << (4 + r); e1 = 0.f; }
            lsum[r] += e0 + e1;
        }
        mb0 = (mb0 >> 8) | (mb1 << 24);
        mb1 = (mb1 >> 8) | (mb2 << 24);
        mb2 = (mb2 >> 8) | (mb3 << 24);
        mb3 = (mb3 >> 8) | (fl << 24);
    }

    // ---- row sums: reduce the 16 lanes per group, then cross-wave via LDS ----
    #pragma unroll
    for (int off = 8; off >= 1; off >>= 1)
        #pragma unroll
        for (int r = 0; r < 4; ++r)
            lsum[r] += __shfl_xor(lsum[r], off, 64);
    if (li == 0) {
        #pragma unroll
        for (int r = 0; r < 4; ++r) wsum[wave][g * 4 + r] = lsum[r];
    }
    __syncthreads();
    if (t < QT) inv_l[t] = 1.0f / (wsum[0][t] + wsum[1][t] + wsum[2][t] + wsum[3][t]);
    __syncthreads();
    float invl[4];
    #pragma unroll
    for (int r = 0; r < 4; ++r) invl[r] = inv_l[g * 4 + r];

    // ---- sweep 2: recompute scores, write normalized attn, P@V. NO barriers. ----
    f32x4 cacc[4] = {{0.f,0.f,0.f,0.f},{0.f,0.f,0.f,0.f},{0.f,0.f,0.f,0.f},{0.f,0.f,0.f,0.f}};
    unsigned short* bw = bnc + wave * 512;                     // 1 KB per wave, wave-local

    #pragma unroll 1
    for (int tl = 0; tl < 16; ++tl) {
        f32x4 s0 = {0.f,0.f,0.f,0.f}, s1 = {0.f,0.f,0.f,0.f};
        qk(tl, s0, s1);
        const unsigned int fl = mb0 & 0xffu;
        mb0 = (mb0 >> 8) | (mb1 << 24);
        mb1 = (mb1 >> 8) | (mb2 << 24);
        mb2 = (mb2 >> 8) | (mb3 << 24);
        mb3 >>= 8;
        const int kg0 = tl * KTL + wave * 32 + li;
        #pragma unroll
        for (int r = 0; r < 4; ++r) {
            float e0 = ((fl >> r)       & 1u) ? 0.f : __expf(s0[r] * SCALE);
            float e1 = ((fl >> (4 + r)) & 1u) ? 0.f : __expf(s1[r] * SCALE);
            const size_t ao = (size_t)(g * 4 + r) * SS + kg0;
            attb[ao]      = e0 * invl[r];
            attb[ao + 16] = e1 * invl[r];
            // bounce (q^blk swizzle: 4-way max on b16 writes):
            // value (q, kk) -> ushort ((kk>>3)*16 + (q ^ (kk>>3)))*8 + (kk&7)
            const int q = g * 4 + r;
            const int b0 = li >> 3, b1 = (li + 16) >> 3;
            bw[((b0 * 16 + (q ^ b0)) << 3) + (li & 7)] = (unsigned short)pk2bf(e0, 0.f);
            bw[((b1 * 16 + (q ^ b1)) << 3) + (li & 7)] = (unsigned short)pk2bf(e1, 0.f);
        }
        // P A-frag: lane wants (q=li, k=g*8+j) -> block g*16 + (li^g), 16 B contiguous
        B8 pf;
        pf.v = *(const bf16x8*)(bw + ((g * 16 + (li ^ g)) << 3));
        const size_t vcol = (size_t)tl * KTL + wave * 32 + g * 8;
        #pragma unroll
        for (int c = 0; c < 4; ++c) {
            const size_t voff = (size_t)(c * 16 + li) * SS + vcol;
            B8 vh, vl;
            vh.v = *(const bf16x8*)(Vhb + voff);               // L2-hit
            vl.v = *(const bf16x8*)(Vlb + voff);
            cacc[c] = __builtin_amdgcn_mfma_f32_16x16x32_bf16(pf.v, vh.v, cacc[c], 0, 0, 0);
            cacc[c] = __builtin_amdgcn_mfma_f32_16x16x32_bf16(pf.v, vl.v, cacc[c], 0, 0, 0);
        }
    }

    // ---- ctx: cross-wave reduce via scratch (bnc dead), scale by 1/L ----
    __syncthreads();
    {
        const int row = wave * 64 + l;                         // 256 rows x stride 17 floats
        #pragma unroll
        for (int c = 0; c < 4; ++c)
            #pragma unroll
            for (int r = 0; r < 4; ++r)
                scr[row * 17 + c * 4 + r] = cacc[c][r];
    }
    __syncthreads();
    {
        const int q = t >> 4, d0 = (t & 15) * 4;
        float4 o;
        float* op = &o.x;
        #pragma unroll
        for (int dd = 0; dd < 4; ++dd) {
            const int d    = d0 + dd;
            const int lane = (q >> 2) * 16 + (d & 15);
            const int idx  = lane * 17 + (d >> 4) * 4 + (q & 3);
            float s = 0.f;
            #pragma unroll
            for (int w = 0; w < 4; ++w) s += scr[w * 64 * 17 + idx];
            op[dd] = s * inv_l[q];
        }
        *(float4*)(ctx + ((size_t)(b * SS + q0 + q)) * DD + d0) = o;
    }
}

extern "C" void kernel_launch(void* const* d_in, const int* in_sizes, int n_in,
                              void* d_out, int out_size, void* d_ws, size_t ws_size,
                              hipStream_t stream) {
    const float* Q = (const float*)d_in[0];
    const float* K = (const float*)d_in[1];
    const float* V = (const float*)d_in[2];
    const int*   M = (const int*)d_in[3];
    float* ctx  = (float*)d_out;                               // [32,2048,64]
    float* attn = (float*)d_out + (size_t)BB * SS * DD;        // [32,2048,2048]

    const size_t NE = (size_t)BB * SS * DD;                    // 4,194,304 elems
    unsigned short* Kbf = (unsigned short*)d_ws;               // 8 MB
    unsigned short* VTh = Kbf + NE;                            // 8 MB
    unsigned short* VTl = VTh + NE;                            // 8 MB (total 24 MB of ws)

    prepK<<<dim3((unsigned)(NE / 8 / NTH)), dim3(NTH), 0, stream>>>(K, Kbf);
    prepV<<<dim3(BB * (SS / KTL)), dim3(NTH), 0, stream>>>(V, VTh, VTl);
    sdpa_mfma2<<<dim3(BB * (SS / QT)), dim3(NTH), 0, stream>>>(Q, M, Kbf, VTh, VTl, ctx, attn);
}